// Round 20
// baseline (214.053 us; speedup 1.0000x reference)
//
#include <hip/hip_runtime.h>
#include <hip/hip_bf16.h>
#include <math.h>

#define B_  32
#define L_  4096
#define H_  512
#define V_  32000
#define MBLK 128

typedef __attribute__((ext_vector_type(4))) float f32x4;
typedef __attribute__((ext_vector_type(2))) float f32x2;
typedef __attribute__((ext_vector_type(8))) short short8;
typedef __attribute__((ext_vector_type(4))) unsigned short u16x4;

__device__ __forceinline__ unsigned short bf16_rne(float x){
  union { float f; unsigned int u; } v; v.f = x;
  unsigned int u = v.u;
  return (unsigned short)((u + 0x7FFFu + ((u >> 16) & 1u)) >> 16);
}
__device__ __forceinline__ float bf16_f32(unsigned short h){
  union { unsigned int u; float f; } v; v.u = ((unsigned int)h) << 16;
  return v.f;
}
// cheap tanh: exact saturation, ~1e-6 abs err
__device__ __forceinline__ float tanh_cheap(float x){
  float e = __expf(x + x);
  return 1.0f - 2.0f * __builtin_amdgcn_rcpf(e + 1.0f);
}
// packed f32x8 -> bf16x8 via v_cvt_pk_bf16_f32
__device__ __forceinline__ short8 cvt8(f32x4 a, f32x4 b){
  union { __hip_bfloat162 h[4]; short8 s; } u;
  u.h[0] = __float22bfloat162_rn(make_float2(a[0], a[1]));
  u.h[1] = __float22bfloat162_rn(make_float2(a[2], a[3]));
  u.h[2] = __float22bfloat162_rn(make_float2(b[0], b[1]));
  u.h[3] = __float22bfloat162_rn(make_float2(b[2], b[3]));
  return u.s;
}

// ---- fused: [0,128) convert W2->w2t transposed bf16; [128,384) gates -----
__global__ __launch_bounds__(256) void k_misc1(
    const float* __restrict__ w2, unsigned short* __restrict__ w2t,
    const float* __restrict__ x, const float* __restrict__ h0,
    const float* __restrict__ Wih, const float* __restrict__ Whh,
    const float* __restrict__ bih, const float* __restrict__ bhh,
    float* __restrict__ gates){
  int bx = blockIdx.x, t = threadIdx.x;
  if (bx < 128){
    int idx = bx * 256 + t;            // 32768 = 64 kc x 512 j
    int j = idx & 511, kc = idx >> 9;
    const float* src = w2 + j*512 + kc*8;
    f32x4 a = *(const f32x4*)src;
    f32x4 b = *(const f32x4*)(src + 4);
    *(short8*)(w2t + (long)(kc*512 + j)*8) = cvt8(a, b);
    return;
  }
  int bx2 = bx - 128;                  // 0..255: jblk = bx2&7, b = bx2>>3
  int jblk = bx2 & 7, b = bx2 >> 3;
  __shared__ float sx[H_], sh[H_];
  sx[t] = x[b*H_ + t]; sx[t+256] = x[b*H_ + t + 256];
  sh[t] = h0[b*H_ + t]; sh[t+256] = h0[b*H_ + t + 256];
  __syncthreads();
  int j = jblk * 256 + t;
  const float* wi = Wih + j*H_;
  const float* wh = Whh + j*H_;
  float acc = bih[j] + bhh[j];
  #pragma unroll 4
  for (int k = 0; k < H_; k += 4) {
    f32x4 a = *(const f32x4*)(wi + k);
    f32x4 c = *(const f32x4*)(wh + k);
    acc += a[0]*sx[k] + a[1]*sx[k+1] + a[2]*sx[k+2] + a[3]*sx[k+3];
    acc += c[0]*sh[k] + c[1]*sh[k+1] + c[2]*sh[k+2] + c[3]*sh[k+3];
  }
  gates[b*2048 + j] = acc;
}

// ---- fused LSTM + q: grid (2,32); block recomputes h[512] for its b ------
__global__ __launch_bounds__(256) void k_lq(
    const float* __restrict__ gates, const float* __restrict__ c0,
    float* __restrict__ out_h, float* __restrict__ out_c, float* __restrict__ cc,
    unsigned short* __restrict__ ccb,
    const float* __restrict__ W1, const float* __restrict__ b1,
    float* __restrict__ q){
  __shared__ float shh[H_];
  int jh = blockIdx.x, b = blockIdx.y, t = threadIdx.x;
  const float* g = gates + b*2048;
  #pragma unroll
  for (int u = 0; u < 2; ++u){
    int hh = t + u*256;
    float gi = g[hh], gf = g[512+hh], gg = g[1024+hh], go = g[1536+hh];
    float si = 1.f/(1.f+expf(-gi));
    float sf = 1.f/(1.f+expf(-gf));
    float so = 1.f/(1.f+expf(-go));
    float c = sf * c0[b*512 + hh] + si * tanhf(gg);
    float h = so * tanhf(c);
    shh[hh] = h;
    if (jh == 0){
      out_h[b*512 + hh] = h; out_c[b*512 + hh] = c;
      cc[b*1024 + hh] = h;
      ccb[b*1024 + hh] = bf16_rne(h);
    }
  }
  __syncthreads();
  int j = jh*256 + t;
  const float* w = W1 + j*H_;
  float acc = b1[j];
  #pragma unroll 4
  for (int k = 0; k < H_; k += 4){
    f32x4 a = *(const f32x4*)(w + k);
    acc += a[0]*shh[k] + a[1]*shh[k+1] + a[2]*shh[k+2] + a[3]*shh[k+3];
  }
  q[b*H_ + j] = acc;
}

// ---------- fused scores+softmax+context: BK=128 mega-steps ---------------
// 1024 blocks x 512 thr (8 waves), (512,2). Persistent tile Adoc[8][128][8][8]
// (128 KB), swizzle chunk' = c ^ (row&7). w2t coalesced B. 128 MFMA/wave
// between barriers. setprio REMOVED (m190: negative in barrier-lockstep
// structures); mega-step loop fully unrolled.
__global__ __launch_bounds__(512, 2) void k_scores_ctx(
    const float* __restrict__ doc, const unsigned short* __restrict__ w2t,
    const float* __restrict__ qv,
    const float* __restrict__ w2b, const float* __restrict__ u1,
    const int* __restrict__ mask,
    float* __restrict__ ctxp, float* __restrict__ bm, float* __restrict__ bs){
  __shared__ short Adoc[8][MBLK][8][8];      // 128 KB [step][row][chunk'][e]
  __shared__ float2 s_qu[512];               // 4 KB
  __shared__ float s_part[8][MBLK];          // 4 KB
  __shared__ float e_arr[MBLK];              // 512 B
  __shared__ float wred[4];
  __shared__ float cpart[2][512];            // 4 KB
  int t = threadIdx.x;
  int row0 = blockIdx.x * MBLK;
  int b = row0 >> 12;
  s_qu[t] = make_float2(qv[b*512 + t] + w2b[t], u1[t]);

  // staging mapping: thread = (row sr = t>>2, 16-float group sg = t&3)
  int sr = t >> 2;
  int sg = t & 3;
  const float* dbase = doc + (((long)(row0 + sr)) << 9) + sg*16;
  int wc0 = (2*sg)     ^ (sr & 7);
  int wc1 = (2*sg + 1) ^ (sr & 7);

  int wave = t >> 6, lane = t & 63;
  int lrow = lane & 15, lk = lane >> 4;
  int sw = lrow & 7;
  int j0 = wave * 64;
  const unsigned short* pbh = w2t + (long)(lk*512 + j0 + lrow)*8;

  f32x4 acc[8][4];  // [mt][jj]
  #pragma unroll
  for (int mt = 0; mt < 8; ++mt)
    #pragma unroll
    for (int jj = 0; jj < 4; ++jj)
      acc[mt][jj] = (f32x4){0.f, 0.f, 0.f, 0.f};

  { // prologue: stage sub-steps 0 and 1
    #pragma unroll
    for (int slot = 0; slot < 2; ++slot){
      const float* p = dbase + slot*64;
      f32x4 v0 = *(const f32x4*)(p);
      f32x4 v1 = *(const f32x4*)(p + 4);
      f32x4 v2 = *(const f32x4*)(p + 8);
      f32x4 v3 = *(const f32x4*)(p + 12);
      *(short8*)&Adoc[slot][sr][wc0][0] = cvt8(v0, v1);
      *(short8*)&Adoc[slot][sr][wc1][0] = cvt8(v2, v3);
    }
  }
  __syncthreads();

#define SUBSTEP(S_)                                                           \
  {                                                                           \
    const int s_ = (S_);                                                      \
    short8 bh[8];                                                             \
    {                                                                         \
      const unsigned short* pb = pbh + (long)s_*8*512*8;                      \
      _Pragma("unroll")                                                       \
      for (int jj = 0; jj < 4; ++jj){                                         \
        bh[jj]   = *(const short8*)(pb + jj*128);                             \
        bh[4+jj] = *(const short8*)(pb + 4*512*8 + jj*128);                   \
      }                                                                       \
    }                                                                         \
    _Pragma("unroll")                                                         \
    for (int ktl = 0; ktl < 2; ++ktl){                                        \
      short8 a[8];                                                            \
      _Pragma("unroll")                                                       \
      for (int mt = 0; mt < 8; ++mt)                                          \
        a[mt] = *(const short8*)&Adoc[s_][mt*16 + lrow][(ktl*4 + lk) ^ sw][0];\
      _Pragma("unroll")                                                       \
      for (int jj = 0; jj < 4; ++jj)                                          \
        _Pragma("unroll")                                                     \
        for (int mt = 0; mt < 8; ++mt)                                        \
          acc[mt][jj] = __builtin_amdgcn_mfma_f32_16x16x32_bf16(              \
              bh[ktl*4 + jj], a[mt], acc[mt][jj], 0, 0, 0);                   \
    }                                                                         \
  }

  #pragma unroll
  for (int S = 0; S < 4; ++S){
    int s0 = S*2;
    f32x4 pfa0, pfa1, pfa2, pfa3, pfb0, pfb1, pfb2, pfb3;
    {
      const int s_ = s0;
      short8 bh[8];
      {
        const unsigned short* pb = pbh + (long)s_*8*512*8;
        #pragma unroll
        for (int jj = 0; jj < 4; ++jj){
          bh[jj]   = *(const short8*)(pb + jj*128);
          bh[4+jj] = *(const short8*)(pb + 4*512*8 + jj*128);
        }
      }
      if (S < 3){
        const float* pa = dbase + (s0+2)*64;
        const float* pbf = dbase + (s0+3)*64;
        pfa0 = *(const f32x4*)(pa);
        pfa1 = *(const f32x4*)(pa + 4);
        pfa2 = *(const f32x4*)(pa + 8);
        pfa3 = *(const f32x4*)(pa + 12);
        pfb0 = *(const f32x4*)(pbf);
        pfb1 = *(const f32x4*)(pbf + 4);
        pfb2 = *(const f32x4*)(pbf + 8);
        pfb3 = *(const f32x4*)(pbf + 12);
      }
      #pragma unroll
      for (int ktl = 0; ktl < 2; ++ktl){
        short8 a[8];
        #pragma unroll
        for (int mt = 0; mt < 8; ++mt)
          a[mt] = *(const short8*)&Adoc[s_][mt*16 + lrow][(ktl*4 + lk) ^ sw][0];
        #pragma unroll
        for (int jj = 0; jj < 4; ++jj)
          #pragma unroll
          for (int mt = 0; mt < 8; ++mt)
            acc[mt][jj] = __builtin_amdgcn_mfma_f32_16x16x32_bf16(
                bh[ktl*4 + jj], a[mt], acc[mt][jj], 0, 0, 0);
      }
    }
    SUBSTEP(s0 + 1)
    if (S < 3){
      *(short8*)&Adoc[s0+2][sr][wc0][0] = cvt8(pfa0, pfa1);
      *(short8*)&Adoc[s0+2][sr][wc1][0] = cvt8(pfa2, pfa3);
      *(short8*)&Adoc[s0+3][sr][wc0][0] = cvt8(pfb0, pfb1);
      *(short8*)&Adoc[s0+3][sr][wc1][0] = cvt8(pfb2, pfb3);
      __syncthreads();
    }
  }
#undef SUBSTEP

  // ---- epilogue: tanh + u1-dot over wave's 64 j's, per m-row
  #pragma unroll
  for (int mt = 0; mt < 8; ++mt){
    float p = 0.f;
    #pragma unroll
    for (int jj = 0; jj < 4; ++jj){
      #pragma unroll
      for (int r = 0; r < 4; ++r){
        int j = j0 + jj*16 + lk*4 + r;
        float2 qu = s_qu[j];
        p += tanh_cheap(acc[mt][jj][r] + qu.x) * qu.y;
      }
    }
    p += __shfl_xor(p, 16);
    p += __shfl_xor(p, 32);
    if (lane < 16) s_part[wave][mt*16 + lrow] = p;
  }
  __syncthreads();

  // ---- block-local softmax over this tile's 128 rows (waves 0,1)
  float sl = 0.f;
  bool ok = false;
  if (t < MBLK){
    #pragma unroll
    for (int w = 0; w < 8; ++w) sl += s_part[w][t];
    ok = mask[row0 + t] != 0;
    sl = ok ? sl : -INFINITY;
    float m = sl;
    #pragma unroll
    for (int o = 1; o < 64; o <<= 1) m = fmaxf(m, __shfl_xor(m, o));
    if (lane == 0) wred[wave] = m;
  }
  __syncthreads();
  if (t < MBLK){
    float mb = fmaxf(wred[0], wred[1]);
    float e = ok ? __expf(sl - mb) : 0.f;
    float es = e;
    #pragma unroll
    for (int o = 1; o < 64; o <<= 1) es += __shfl_xor(es, o);
    if (lane == 0) wred[2 + wave] = es;
    e_arr[t] = e;
    if (t == 0) bm[blockIdx.x] = mb;
  }
  __syncthreads();
  if (t == 0) bs[blockIdx.x] = wred[2] + wred[3];

  // ---- ctx partial from resident tile: ctxp[h] = sum_l e_l * doc[l][h]
  {
    int p = t & 255, half = t >> 8;     // col pair (2p,2p+1); rows half*64..+64
    int h0 = 2*p;
    int sstep = h0 >> 6;                // K-step
    int c = (h0 >> 3) & 7;              // chunk within step
    int e = h0 & 7;                     // elem (even)
    float a0 = 0.f, a1 = 0.f;
    int l0 = half * 64;
    #pragma unroll 8
    for (int l = l0; l < l0 + 64; ++l){
      int cp = c ^ (l & 7);
      unsigned v = *(const unsigned*)((const char*)&Adoc[sstep][l][cp][0] + e*2);
      float el = e_arr[l];
      a0 += el * bf16_f32((unsigned short)(v & 0xffff));
      a1 += el * bf16_f32((unsigned short)(v >> 16));
    }
    cpart[half][2*p]   = a0;
    cpart[half][2*p+1] = a1;
  }
  __syncthreads();
  ctxp[(long)blockIdx.x * 512 + t] = cpart[0][t] + cpart[1][t];
}

// ---------------- combine: merge 32 block-partials per batch row ----------
__global__ __launch_bounds__(512) void k_combine(
    const float* __restrict__ ctxp, const float* __restrict__ bm,
    const float* __restrict__ bs, unsigned short* __restrict__ ccb){
  __shared__ float sw[32];
  __shared__ float sT;
  int b = blockIdx.x, t = threadIdx.x;
  if (t < 32){
    float m = bm[b*32 + t], s = bs[b*32 + t];
    float M = m;
    #pragma unroll
    for (int o = 1; o < 32; o <<= 1) M = fmaxf(M, __shfl_xor(M, o));
    float w = (m == -INFINITY) ? 0.f : __expf(m - M);
    float ts = s * w;
    #pragma unroll
    for (int o = 1; o < 32; o <<= 1) ts += __shfl_xor(ts, o);
    sw[t] = w;
    if (t == 0) sT = ts;
  }
  __syncthreads();
  float invT = 1.f / sT;
  const float* cp = ctxp + (long)b*32*512 + t;
  float acc = 0.f;
  #pragma unroll 8
  for (int blk = 0; blk < 32; ++blk) acc += cp[blk*512] * sw[blk];
  ccb[b*1024 + 512 + t] = bf16_rne(acc * invT);
}

// ---------------- output = cc @ Wout^T + bout, direct stores ---------------
// 500 blocks x 256 thr (4 waves), 64 v-rows/block -> 2 blocks/CU on 250 CUs.
__global__ __launch_bounds__(256, 2) void k_out(
    const unsigned short* __restrict__ ccb, const float* __restrict__ Wout,
    const float* __restrict__ bout, float* __restrict__ out){
  __shared__ short Ccb[32][128][8];      // 64 KB
  int t = threadIdx.x, wave = t >> 6, lane = t & 63;
  int v0 = blockIdx.x * 64;
  #pragma unroll
  for (int i = 0; i < 16; ++i){
    int c16 = i*256 + t;               // 16B-chunk index over 4096
    int bb = c16 >> 7, ch = c16 & 127;
    int chsw = (ch & ~7) | ((ch & 7) ^ (bb & 7));
    *(short8*)&Ccb[bb][chsw][0] = *(const short8*)(ccb + c16*8);
  }
  __syncthreads();

  int lrow = lane & 15, lk = lane >> 4;
  int vrow = v0 + wave*16 + lrow;
  const float* wptr = Wout + (long)vrow*1024 + lk*8;
  f32x4 acc[2];
  acc[0] = (f32x4){0.f,0.f,0.f,0.f};
  acc[1] = (f32x4){0.f,0.f,0.f,0.f};
  int sw = lrow & 7;
  f32x4 w0 = *(const f32x4*)(wptr);
  f32x4 w1 = *(const f32x4*)(wptr + 4);
  #pragma unroll 4
  for (int ks = 0; ks < 32; ++ks){
    f32x4 nw0, nw1;
    if (ks < 31){
      nw0 = *(const f32x4*)(wptr + (ks+1)*32);
      nw1 = *(const f32x4*)(wptr + (ks+1)*32 + 4);
    }
    short8 bfrag = cvt8(w0, w1);
    int ch = ks*4 + lk;
    int chsw = (ch & ~7) | ((ch & 7) ^ sw);
    short8 a0 = *(const short8*)&Ccb[lrow][chsw][0];
    short8 a1 = *(const short8*)&Ccb[16 + lrow][chsw][0];
    acc[0] = __builtin_amdgcn_mfma_f32_16x16x32_bf16(bfrag, a0, acc[0], 0, 0, 0);
    acc[1] = __builtin_amdgcn_mfma_f32_16x16x32_bf16(bfrag, a1, acc[1], 0, 0, 0);
    w0 = nw0; w1 = nw1;
  }
  int vcol = v0 + wave*16 + lk*4;
  f32x4 bo4 = *(const f32x4*)&bout[vcol];
  #pragma unroll
  for (int mt = 0; mt < 2; ++mt){
    f32x4 res;
    res[0] = acc[mt][0] + bo4[0];
    res[1] = acc[mt][1] + bo4[1];
    res[2] = acc[mt][2] + bo4[2];
    res[3] = acc[mt][3] + bo4[3];
    *(f32x4*)&out[(long)(mt*16 + lrow)*V_ + vcol] = res;
  }
}

extern "C" void kernel_launch(void* const* d_in, const int* in_sizes, int n_in,
                              void* d_out, int out_size, void* d_ws, size_t ws_size,
                              hipStream_t stream){
  const float* x    = (const float*)d_in[0];
  const float* h0   = (const float*)d_in[1];
  const float* c0   = (const float*)d_in[2];
  const float* doc  = (const float*)d_in[3];
  const int*   mask = (const int*)d_in[4];
  const float* Wih  = (const float*)d_in[5];
  const float* Whh  = (const float*)d_in[6];
  const float* bih  = (const float*)d_in[7];
  const float* bhh  = (const float*)d_in[8];
  const float* W1   = (const float*)d_in[9];
  const float* b1   = (const float*)d_in[10];
  const float* W2   = (const float*)d_in[11];
  const float* b2   = (const float*)d_in[12];
  const float* u1   = (const float*)d_in[13];
  const float* Wo   = (const float*)d_in[14];
  const float* bo   = (const float*)d_in[15];
  float* out  = (float*)d_out;
  float* outh = out + B_*V_;
  float* outc = outh + B_*H_;

  float* ws    = (float*)d_ws;
  float* gates = ws;                  // 65536 f32
  float* q     = gates + 65536;       // 16384
  float* cc    = q + 16384;           // 32768
  float* ctxp  = cc + 32768;          // 1024*512 = 524288
  float* bm    = ctxp + 524288;       // 1024
  float* bs    = bm + 1024;           // 1024
  unsigned short* w2t = (unsigned short*)(bs + 1024);       // 262144 u16
  unsigned short* ccb = w2t + 262144;                       // 32768 u16

  hipLaunchKernelGGL(k_misc1, dim3(384), dim3(256), 0, stream,
                     W2, w2t, x, h0, Wih, Whh, bih, bhh, gates);
  hipLaunchKernelGGL(k_lq, dim3(2, 32), dim3(256), 0, stream,
                     gates, c0, outh, outc, cc, ccb, W1, b1, q);
  hipLaunchKernelGGL(k_scores_ctx, dim3(1024), dim3(512), 0, stream, doc, w2t, q, b2, u1, mask, ctxp, bm, bs);
  hipLaunchKernelGGL(k_combine, dim3(32), dim3(512), 0, stream, ctxp, bm, bs, ccb);
  hipLaunchKernelGGL(k_out, dim3(500), dim3(256), 0, stream, ccb, Wo, bo, out);
}

// Round 21
// 200.368 us; speedup vs baseline: 1.0683x; 1.0683x over previous
//
#include <hip/hip_runtime.h>
#include <hip/hip_bf16.h>
#include <math.h>

#define B_  32
#define L_  4096
#define H_  512
#define V_  32000
#define MBLK 128

typedef __attribute__((ext_vector_type(4))) float f32x4;
typedef __attribute__((ext_vector_type(2))) float f32x2;
typedef __attribute__((ext_vector_type(8))) short short8;
typedef __attribute__((ext_vector_type(4))) unsigned short u16x4;

__device__ __forceinline__ unsigned short bf16_rne(float x){
  union { float f; unsigned int u; } v; v.f = x;
  unsigned int u = v.u;
  return (unsigned short)((u + 0x7FFFu + ((u >> 16) & 1u)) >> 16);
}
__device__ __forceinline__ float bf16_f32(unsigned short h){
  union { unsigned int u; float f; } v; v.u = ((unsigned int)h) << 16;
  return v.f;
}
// cheap tanh: exact saturation, ~1e-6 abs err
__device__ __forceinline__ float tanh_cheap(float x){
  float e = __expf(x + x);
  return 1.0f - 2.0f * __builtin_amdgcn_rcpf(e + 1.0f);
}
// packed f32x8 -> bf16x8 via v_cvt_pk_bf16_f32
__device__ __forceinline__ short8 cvt8(f32x4 a, f32x4 b){
  union { __hip_bfloat162 h[4]; short8 s; } u;
  u.h[0] = __float22bfloat162_rn(make_float2(a[0], a[1]));
  u.h[1] = __float22bfloat162_rn(make_float2(a[2], a[3]));
  u.h[2] = __float22bfloat162_rn(make_float2(b[0], b[1]));
  u.h[3] = __float22bfloat162_rn(make_float2(b[2], b[3]));
  return u.s;
}

// ---- fused: [0,128) convert W2->w2t transposed bf16; [128,384) gates -----
__global__ __launch_bounds__(256) void k_misc1(
    const float* __restrict__ w2, unsigned short* __restrict__ w2t,
    const float* __restrict__ x, const float* __restrict__ h0,
    const float* __restrict__ Wih, const float* __restrict__ Whh,
    const float* __restrict__ bih, const float* __restrict__ bhh,
    float* __restrict__ gates){
  int bx = blockIdx.x, t = threadIdx.x;
  if (bx < 128){
    int idx = bx * 256 + t;            // 32768 = 64 kc x 512 j
    int j = idx & 511, kc = idx >> 9;
    const float* src = w2 + j*512 + kc*8;
    f32x4 a = *(const f32x4*)src;
    f32x4 b = *(const f32x4*)(src + 4);
    *(short8*)(w2t + (long)(kc*512 + j)*8) = cvt8(a, b);
    return;
  }
  int bx2 = bx - 128;                  // 0..255: jblk = bx2&7, b = bx2>>3
  int jblk = bx2 & 7, b = bx2 >> 3;
  __shared__ float sx[H_], sh[H_];
  sx[t] = x[b*H_ + t]; sx[t+256] = x[b*H_ + t + 256];
  sh[t] = h0[b*H_ + t]; sh[t+256] = h0[b*H_ + t + 256];
  __syncthreads();
  int j = jblk * 256 + t;
  const float* wi = Wih + j*H_;
  const float* wh = Whh + j*H_;
  float acc = bih[j] + bhh[j];
  #pragma unroll 4
  for (int k = 0; k < H_; k += 4) {
    f32x4 a = *(const f32x4*)(wi + k);
    f32x4 c = *(const f32x4*)(wh + k);
    acc += a[0]*sx[k] + a[1]*sx[k+1] + a[2]*sx[k+2] + a[3]*sx[k+3];
    acc += c[0]*sh[k] + c[1]*sh[k+1] + c[2]*sh[k+2] + c[3]*sh[k+3];
  }
  gates[b*2048 + j] = acc;
}

// ---- fused LSTM + q: grid (2,32); block recomputes h[512] for its b ------
__global__ __launch_bounds__(256) void k_lq(
    const float* __restrict__ gates, const float* __restrict__ c0,
    float* __restrict__ out_h, float* __restrict__ out_c, float* __restrict__ cc,
    unsigned short* __restrict__ ccb,
    const float* __restrict__ W1, const float* __restrict__ b1,
    float* __restrict__ q){
  __shared__ float shh[H_];
  int jh = blockIdx.x, b = blockIdx.y, t = threadIdx.x;
  const float* g = gates + b*2048;
  #pragma unroll
  for (int u = 0; u < 2; ++u){
    int hh = t + u*256;
    float gi = g[hh], gf = g[512+hh], gg = g[1024+hh], go = g[1536+hh];
    float si = 1.f/(1.f+expf(-gi));
    float sf = 1.f/(1.f+expf(-gf));
    float so = 1.f/(1.f+expf(-go));
    float c = sf * c0[b*512 + hh] + si * tanhf(gg);
    float h = so * tanhf(c);
    shh[hh] = h;
    if (jh == 0){
      out_h[b*512 + hh] = h; out_c[b*512 + hh] = c;
      cc[b*1024 + hh] = h;
      ccb[b*1024 + hh] = bf16_rne(h);
    }
  }
  __syncthreads();
  int j = jh*256 + t;
  const float* w = W1 + j*H_;
  float acc = b1[j];
  #pragma unroll 4
  for (int k = 0; k < H_; k += 4){
    f32x4 a = *(const f32x4*)(w + k);
    acc += a[0]*shh[k] + a[1]*shh[k+1] + a[2]*shh[k+2] + a[3]*shh[k+3];
  }
  q[b*H_ + j] = acc;
}

// ---------- fused scores+softmax+context: BK=128 mega-steps (R19 best) ----
// 1024 blocks x 512 thr (8 waves), (512,2). Persistent tile Adoc[8][128][8][8]
// (128 KB), swizzle chunk' = c ^ (row&7). w2t coalesced B. 128 MFMA/wave
// between barriers; pf issued after sub0's B loads; setprio around MFMA
// clusters (R20 A/B: removing it regressed ~8 us).
__global__ __launch_bounds__(512, 2) void k_scores_ctx(
    const float* __restrict__ doc, const unsigned short* __restrict__ w2t,
    const float* __restrict__ qv,
    const float* __restrict__ w2b, const float* __restrict__ u1,
    const int* __restrict__ mask,
    float* __restrict__ ctxp, float* __restrict__ bm, float* __restrict__ bs){
  __shared__ short Adoc[8][MBLK][8][8];      // 128 KB [step][row][chunk'][e]
  __shared__ float2 s_qu[512];               // 4 KB
  __shared__ float s_part[8][MBLK];          // 4 KB
  __shared__ float e_arr[MBLK];              // 512 B
  __shared__ float wred[4];
  __shared__ float cpart[2][512];            // 4 KB
  int t = threadIdx.x;
  int row0 = blockIdx.x * MBLK;
  int b = row0 >> 12;
  s_qu[t] = make_float2(qv[b*512 + t] + w2b[t], u1[t]);

  // staging mapping: thread = (row sr = t>>2, 16-float group sg = t&3)
  int sr = t >> 2;
  int sg = t & 3;
  const float* dbase = doc + (((long)(row0 + sr)) << 9) + sg*16;
  int wc0 = (2*sg)     ^ (sr & 7);
  int wc1 = (2*sg + 1) ^ (sr & 7);

  int wave = t >> 6, lane = t & 63;
  int lrow = lane & 15, lk = lane >> 4;
  int sw = lrow & 7;
  int j0 = wave * 64;
  const unsigned short* pbh = w2t + (long)(lk*512 + j0 + lrow)*8;

  f32x4 acc[8][4];  // [mt][jj]
  #pragma unroll
  for (int mt = 0; mt < 8; ++mt)
    #pragma unroll
    for (int jj = 0; jj < 4; ++jj)
      acc[mt][jj] = (f32x4){0.f, 0.f, 0.f, 0.f};

  { // prologue: stage sub-steps 0 and 1
    #pragma unroll
    for (int slot = 0; slot < 2; ++slot){
      const float* p = dbase + slot*64;
      f32x4 v0 = *(const f32x4*)(p);
      f32x4 v1 = *(const f32x4*)(p + 4);
      f32x4 v2 = *(const f32x4*)(p + 8);
      f32x4 v3 = *(const f32x4*)(p + 12);
      *(short8*)&Adoc[slot][sr][wc0][0] = cvt8(v0, v1);
      *(short8*)&Adoc[slot][sr][wc1][0] = cvt8(v2, v3);
    }
  }
  __syncthreads();

#define SUBSTEP(S_)                                                           \
  {                                                                           \
    const int s_ = (S_);                                                      \
    short8 bh[8];                                                             \
    {                                                                         \
      const unsigned short* pb = pbh + (long)s_*8*512*8;                      \
      _Pragma("unroll")                                                       \
      for (int jj = 0; jj < 4; ++jj){                                         \
        bh[jj]   = *(const short8*)(pb + jj*128);                             \
        bh[4+jj] = *(const short8*)(pb + 4*512*8 + jj*128);                   \
      }                                                                       \
    }                                                                         \
    _Pragma("unroll")                                                         \
    for (int ktl = 0; ktl < 2; ++ktl){                                        \
      short8 a[8];                                                            \
      _Pragma("unroll")                                                       \
      for (int mt = 0; mt < 8; ++mt)                                          \
        a[mt] = *(const short8*)&Adoc[s_][mt*16 + lrow][(ktl*4 + lk) ^ sw][0];\
      __builtin_amdgcn_s_setprio(1);                                          \
      _Pragma("unroll")                                                       \
      for (int jj = 0; jj < 4; ++jj)                                          \
        _Pragma("unroll")                                                     \
        for (int mt = 0; mt < 8; ++mt)                                        \
          acc[mt][jj] = __builtin_amdgcn_mfma_f32_16x16x32_bf16(              \
              bh[ktl*4 + jj], a[mt], acc[mt][jj], 0, 0, 0);                   \
      __builtin_amdgcn_s_setprio(0);                                          \
    }                                                                         \
  }

  #pragma unroll 1
  for (int S = 0; S < 4; ++S){
    int s0 = S*2;
    f32x4 pfa0, pfa1, pfa2, pfa3, pfb0, pfb1, pfb2, pfb3;
    {
      const int s_ = s0;
      short8 bh[8];
      {
        const unsigned short* pb = pbh + (long)s_*8*512*8;
        #pragma unroll
        for (int jj = 0; jj < 4; ++jj){
          bh[jj]   = *(const short8*)(pb + jj*128);
          bh[4+jj] = *(const short8*)(pb + 4*512*8 + jj*128);
        }
      }
      if (S < 3){
        const float* pa = dbase + (s0+2)*64;
        const float* pbf = dbase + (s0+3)*64;
        pfa0 = *(const f32x4*)(pa);
        pfa1 = *(const f32x4*)(pa + 4);
        pfa2 = *(const f32x4*)(pa + 8);
        pfa3 = *(const f32x4*)(pa + 12);
        pfb0 = *(const f32x4*)(pbf);
        pfb1 = *(const f32x4*)(pbf + 4);
        pfb2 = *(const f32x4*)(pbf + 8);
        pfb3 = *(const f32x4*)(pbf + 12);
      }
      #pragma unroll
      for (int ktl = 0; ktl < 2; ++ktl){
        short8 a[8];
        #pragma unroll
        for (int mt = 0; mt < 8; ++mt)
          a[mt] = *(const short8*)&Adoc[s_][mt*16 + lrow][(ktl*4 + lk) ^ sw][0];
        __builtin_amdgcn_s_setprio(1);
        #pragma unroll
        for (int jj = 0; jj < 4; ++jj)
          #pragma unroll
          for (int mt = 0; mt < 8; ++mt)
            acc[mt][jj] = __builtin_amdgcn_mfma_f32_16x16x32_bf16(
                bh[ktl*4 + jj], a[mt], acc[mt][jj], 0, 0, 0);
        __builtin_amdgcn_s_setprio(0);
      }
    }
    SUBSTEP(s0 + 1)
    if (S < 3){
      *(short8*)&Adoc[s0+2][sr][wc0][0] = cvt8(pfa0, pfa1);
      *(short8*)&Adoc[s0+2][sr][wc1][0] = cvt8(pfa2, pfa3);
      *(short8*)&Adoc[s0+3][sr][wc0][0] = cvt8(pfb0, pfb1);
      *(short8*)&Adoc[s0+3][sr][wc1][0] = cvt8(pfb2, pfb3);
      __syncthreads();
    }
  }
#undef SUBSTEP

  // ---- epilogue: tanh + u1-dot over wave's 64 j's, per m-row
  #pragma unroll
  for (int mt = 0; mt < 8; ++mt){
    float p = 0.f;
    #pragma unroll
    for (int jj = 0; jj < 4; ++jj){
      #pragma unroll
      for (int r = 0; r < 4; ++r){
        int j = j0 + jj*16 + lk*4 + r;
        float2 qu = s_qu[j];
        p += tanh_cheap(acc[mt][jj][r] + qu.x) * qu.y;
      }
    }
    p += __shfl_xor(p, 16);
    p += __shfl_xor(p, 32);
    if (lane < 16) s_part[wave][mt*16 + lrow] = p;
  }
  __syncthreads();

  // ---- block-local softmax over this tile's 128 rows (waves 0,1)
  float sl = 0.f;
  bool ok = false;
  if (t < MBLK){
    #pragma unroll
    for (int w = 0; w < 8; ++w) sl += s_part[w][t];
    ok = mask[row0 + t] != 0;
    sl = ok ? sl : -INFINITY;
    float m = sl;
    #pragma unroll
    for (int o = 1; o < 64; o <<= 1) m = fmaxf(m, __shfl_xor(m, o));
    if (lane == 0) wred[wave] = m;
  }
  __syncthreads();
  if (t < MBLK){
    float mb = fmaxf(wred[0], wred[1]);
    float e = ok ? __expf(sl - mb) : 0.f;
    float es = e;
    #pragma unroll
    for (int o = 1; o < 64; o <<= 1) es += __shfl_xor(es, o);
    if (lane == 0) wred[2 + wave] = es;
    e_arr[t] = e;
    if (t == 0) bm[blockIdx.x] = mb;
  }
  __syncthreads();
  if (t == 0) bs[blockIdx.x] = wred[2] + wred[3];

  // ---- ctx partial from resident tile: ctxp[h] = sum_l e_l * doc[l][h]
  {
    int p = t & 255, half = t >> 8;     // col pair (2p,2p+1); rows half*64..+64
    int h0 = 2*p;
    int sstep = h0 >> 6;                // K-step
    int c = (h0 >> 3) & 7;              // chunk within step
    int e = h0 & 7;                     // elem (even)
    float a0 = 0.f, a1 = 0.f;
    int l0 = half * 64;
    #pragma unroll 8
    for (int l = l0; l < l0 + 64; ++l){
      int cp = c ^ (l & 7);
      unsigned v = *(const unsigned*)((const char*)&Adoc[sstep][l][cp][0] + e*2);
      float el = e_arr[l];
      a0 += el * bf16_f32((unsigned short)(v & 0xffff));
      a1 += el * bf16_f32((unsigned short)(v >> 16));
    }
    cpart[half][2*p]   = a0;
    cpart[half][2*p+1] = a1;
  }
  __syncthreads();
  ctxp[(long)blockIdx.x * 512 + t] = cpart[0][t] + cpart[1][t];
}

// ---------------- combine: merge 32 block-partials per batch row ----------
__global__ __launch_bounds__(512) void k_combine(
    const float* __restrict__ ctxp, const float* __restrict__ bm,
    const float* __restrict__ bs, unsigned short* __restrict__ ccb){
  __shared__ float sw[32];
  __shared__ float sT;
  int b = blockIdx.x, t = threadIdx.x;
  if (t < 32){
    float m = bm[b*32 + t], s = bs[b*32 + t];
    float M = m;
    #pragma unroll
    for (int o = 1; o < 32; o <<= 1) M = fmaxf(M, __shfl_xor(M, o));
    float w = (m == -INFINITY) ? 0.f : __expf(m - M);
    float ts = s * w;
    #pragma unroll
    for (int o = 1; o < 32; o <<= 1) ts += __shfl_xor(ts, o);
    sw[t] = w;
    if (t == 0) sT = ts;
  }
  __syncthreads();
  float invT = 1.f / sT;
  const float* cp = ctxp + (long)b*32*512 + t;
  float acc = 0.f;
  #pragma unroll 8
  for (int blk = 0; blk < 32; ++blk) acc += cp[blk*512] * sw[blk];
  ccb[b*1024 + 512 + t] = bf16_rne(acc * invT);
}

// ---------------- output = cc @ Wout^T + bout, direct stores ---------------
// 500 blocks x 256 thr (4 waves), 64 v-rows/block -> 2 blocks/CU on 250 CUs.
__global__ __launch_bounds__(256, 2) void k_out(
    const unsigned short* __restrict__ ccb, const float* __restrict__ Wout,
    const float* __restrict__ bout, float* __restrict__ out){
  __shared__ short Ccb[32][128][8];      // 64 KB
  int t = threadIdx.x, wave = t >> 6, lane = t & 63;
  int v0 = blockIdx.x * 64;
  #pragma unroll
  for (int i = 0; i < 16; ++i){
    int c16 = i*256 + t;               // 16B-chunk index over 4096
    int bb = c16 >> 7, ch = c16 & 127;
    int chsw = (ch & ~7) | ((ch & 7) ^ (bb & 7));
    *(short8*)&Ccb[bb][chsw][0] = *(const short8*)(ccb + c16*8);
  }
  __syncthreads();

  int lrow = lane & 15, lk = lane >> 4;
  int vrow = v0 + wave*16 + lrow;
  const float* wptr = Wout + (long)vrow*1024 + lk*8;
  f32x4 acc[2];
  acc[0] = (f32x4){0.f,0.f,0.f,0.f};
  acc[1] = (f32x4){0.f,0.f,0.f,0.f};
  int sw = lrow & 7;
  f32x4 w0 = *(const f32x4*)(wptr);
  f32x4 w1 = *(const f32x4*)(wptr + 4);
  #pragma unroll 4
  for (int ks = 0; ks < 32; ++ks){
    f32x4 nw0, nw1;
    if (ks < 31){
      nw0 = *(const f32x4*)(wptr + (ks+1)*32);
      nw1 = *(const f32x4*)(wptr + (ks+1)*32 + 4);
    }
    short8 bfrag = cvt8(w0, w1);
    int ch = ks*4 + lk;
    int chsw = (ch & ~7) | ((ch & 7) ^ sw);
    short8 a0 = *(const short8*)&Ccb[lrow][chsw][0];
    short8 a1 = *(const short8*)&Ccb[16 + lrow][chsw][0];
    acc[0] = __builtin_amdgcn_mfma_f32_16x16x32_bf16(bfrag, a0, acc[0], 0, 0, 0);
    acc[1] = __builtin_amdgcn_mfma_f32_16x16x32_bf16(bfrag, a1, acc[1], 0, 0, 0);
    w0 = nw0; w1 = nw1;
  }
  int vcol = v0 + wave*16 + lk*4;
  f32x4 bo4 = *(const f32x4*)&bout[vcol];
  #pragma unroll
  for (int mt = 0; mt < 2; ++mt){
    f32x4 res;
    res[0] = acc[mt][0] + bo4[0];
    res[1] = acc[mt][1] + bo4[1];
    res[2] = acc[mt][2] + bo4[2];
    res[3] = acc[mt][3] + bo4[3];
    *(f32x4*)&out[(long)(mt*16 + lrow)*V_ + vcol] = res;
  }
}

extern "C" void kernel_launch(void* const* d_in, const int* in_sizes, int n_in,
                              void* d_out, int out_size, void* d_ws, size_t ws_size,
                              hipStream_t stream){
  const float* x    = (const float*)d_in[0];
  const float* h0   = (const float*)d_in[1];
  const float* c0   = (const float*)d_in[2];
  const float* doc  = (const float*)d_in[3];
  const int*   mask = (const int*)d_in[4];
  const float* Wih  = (const float*)d_in[5];
  const float* Whh  = (const float*)d_in[6];
  const float* bih  = (const float*)d_in[7];
  const float* bhh  = (const float*)d_in[8];
  const float* W1   = (const float*)d_in[9];
  const float* b1   = (const float*)d_in[10];
  const float* W2   = (const float*)d_in[11];
  const float* b2   = (const float*)d_in[12];
  const float* u1   = (const float*)d_in[13];
  const float* Wo   = (const float*)d_in[14];
  const float* bo   = (const float*)d_in[15];
  float* out  = (float*)d_out;
  float* outh = out + B_*V_;
  float* outc = outh + B_*H_;

  float* ws    = (float*)d_ws;
  float* gates = ws;                  // 65536 f32
  float* q     = gates + 65536;       // 16384
  float* cc    = q + 16384;           // 32768
  float* ctxp  = cc + 32768;          // 1024*512 = 524288
  float* bm    = ctxp + 524288;       // 1024
  float* bs    = bm + 1024;           // 1024
  unsigned short* w2t = (unsigned short*)(bs + 1024);       // 262144 u16
  unsigned short* ccb = w2t + 262144;                       // 32768 u16

  hipLaunchKernelGGL(k_misc1, dim3(384), dim3(256), 0, stream,
                     W2, w2t, x, h0, Wih, Whh, bih, bhh, gates);
  hipLaunchKernelGGL(k_lq, dim3(2, 32), dim3(256), 0, stream,
                     gates, c0, outh, outc, cc, ccb, W1, b1, q);
  hipLaunchKernelGGL(k_scores_ctx, dim3(1024), dim3(512), 0, stream, doc, w2t, q, b2, u1, mask, ctxp, bm, bs);
  hipLaunchKernelGGL(k_combine, dim3(32), dim3(512), 0, stream, ctxp, bm, bs, ccb);
  hipLaunchKernelGGL(k_out, dim3(500), dim3(256), 0, stream, ccb, Wo, bo, out);
}